// Round 6
// baseline (1716.128 us; speedup 1.0000x reference)
//
#include <hip/hip_runtime.h>
#include <hip/hip_bf16.h>

#define TSTEPS 2048
#define NB 64
#define DH 256
#define NBDH (NB * DH)

typedef __attribute__((ext_vector_type(8))) short short8;
typedef __attribute__((ext_vector_type(4))) float f32x4;

__device__ __forceinline__ unsigned short f2bf(float f) {
  union { float f; unsigned u; } v; v.f = f;
  unsigned u = v.u;
  u += 0x7FFFu + ((u >> 16) & 1u);   // round-to-nearest-even
  return (unsigned short)(u >> 16);
}

__device__ __forceinline__ float fast_tanh(float x) {
  // tanh(x) = 1 - 2/(e^{2x}+1); saturates correctly at +/-1
  float e = __builtin_amdgcn_exp2f(x * 2.885390081777927f);  // e^{2x}
  return 1.0f - 2.0f * __builtin_amdgcn_rcpf(e + 1.0f);
}

// ---- kernel 0: convert the three 256x256 f32 weight mats to bf16 ----
__global__ void cvt_w(const float* __restrict__ a, const float* __restrict__ b,
                      const float* __restrict__ c, unsigned short* __restrict__ dst) {
  int i = blockIdx.x * 256 + threadIdx.x;  // 0 .. 3*65536-1
  const float* s = (i < 65536) ? a : ((i < 131072) ? b : c);
  dst[i] = f2bf(s[i & 65535]);
}

// ---- kernels 1 & 3: C[M,256] = A[M,256] * W[256,256]^T  (W row-major [n][k], bf16)
template <bool A_BF16>
__global__ __launch_bounds__(256) void gemm_nt(
    const void* __restrict__ Aptr, const unsigned short* __restrict__ Wbf,
    float* __restrict__ Cout) {
  const int w = threadIdx.x >> 6, l = threadIdx.x & 63;
  const int m16 = l & 15, kg = l >> 4;
  const long tile0 = ((long)blockIdx.x * 4 + w) * 2;

  short8 afr[2][8];
  for (int ti = 0; ti < 2; ++ti) {
    long row = (tile0 + ti) * 16 + m16;
    if (A_BF16) {
      const unsigned short* ar = (const unsigned short*)Aptr + row * 256 + kg * 8;
      for (int ks = 0; ks < 8; ++ks) afr[ti][ks] = *(const short8*)(ar + ks * 32);
    } else {
      const float* ar = (const float*)Aptr + row * 256 + kg * 8;
      for (int ks = 0; ks < 8; ++ks) {
        const float4* p = (const float4*)(ar + ks * 32);
        float4 f0 = p[0], f1 = p[1];
        short8 s;
        s[0] = (short)f2bf(f0.x); s[1] = (short)f2bf(f0.y);
        s[2] = (short)f2bf(f0.z); s[3] = (short)f2bf(f0.w);
        s[4] = (short)f2bf(f1.x); s[5] = (short)f2bf(f1.y);
        s[6] = (short)f2bf(f1.z); s[7] = (short)f2bf(f1.w);
        afr[ti][ks] = s;
      }
    }
  }
  for (int nt = 0; nt < 16; ++nt) {
    const int n = nt * 16 + m16;
    const unsigned short* wr = Wbf + n * 256 + kg * 8;
    f32x4 acc0 = {0.f, 0.f, 0.f, 0.f}, acc1 = {0.f, 0.f, 0.f, 0.f};
    for (int ks = 0; ks < 8; ++ks) {
      short8 b = *(const short8*)(wr + ks * 32);
      acc0 = __builtin_amdgcn_mfma_f32_16x16x32_bf16(afr[0][ks], b, acc0, 0, 0, 0);
      acc1 = __builtin_amdgcn_mfma_f32_16x16x32_bf16(afr[1][ks], b, acc1, 0, 0, 0);
    }
    for (int r = 0; r < 4; ++r) {
      Cout[(tile0 * 16 + kg * 4 + r) * 256 + n]       = acc0[r];
      Cout[((tile0 + 1) * 16 + kg * 4 + r) * 256 + n] = acc1[r];
    }
  }
}

// ---- kernel 2: sequential scan. 32 blocks x 2 INDEPENDENT batch rows,
// 8 waves x 32 cols. Two independent recurrences interleaved per block: row
// B's MFMA/VALU work fills row A's latency bubbles (LDS latency, MFMA dep
// chains, tanh). One shared lgkm-drain + barrier per iteration.
// h layout per row: LINEAR by column (A-frag order for M=1), double-buffered.
__global__ __launch_bounds__(512, 2) void rnn_scan(
    const float* __restrict__ xp, const unsigned short* __restrict__ Wbf,
    const float* __restrict__ h0, unsigned short* __restrict__ hs) {
  __shared__ unsigned short hA[2][2][256];        // [row][buf][col]
  const int tid = threadIdx.x, w = tid >> 6, l = tid & 63;
  const int b0 = blockIdx.x * 2;                  // two batch rows per block
  const int m16 = l & 15, kg = l >> 4;

  // W_hid B-fragments resident: wave owns cols [w*32, w*32+32), 2 tiles
  short8 bf0[8], bf1[8];
  {
    const unsigned short* wr0 = Wbf + (w * 32 + m16) * 256 + kg * 8;
    const unsigned short* wr1 = Wbf + (w * 32 + 16 + m16) * 256 + kg * 8;
    for (int ks = 0; ks < 8; ++ks) {
      bf0[ks] = *(const short8*)(wr0 + ks * 32);
      bf1[ks] = *(const short8*)(wr1 + ks * 32);
    }
  }

  {
    int r = tid >> 8, c = tid & 255;              // 512 threads = 2 rows x 256
    hA[r][0][c] = f2bf(h0[(b0 + r) * 256 + c]);
  }
  __syncthreads();

  const int col0 = w * 32 + m16;
  const unsigned short* rdpA = &hA[0][0][0] + kg * 8;   // + CUR*256 + ks*32 (imm)
  const unsigned short* rdpB = &hA[1][0][0] + kg * 8;
  const float* xpbA = xp + (long)b0 * 256 + col0;       // + t*NBDH
  const float* xpbB = xpbA + 256;
  unsigned short* hsbA = hs + (long)b0 * 256 + col0;    // + t*NBDH
  unsigned short* hsbB = hsbA + 256;

  // 4-deep xp prefetch rotation, per row
  float xa0[2], xa1[2], xa2[2], xa3[2];
  float xb0[2], xb1[2], xb2[2], xb3[2];
  xa0[0] = xpbA[0];         xa0[1] = xpbA[16];
  xa1[0] = xpbA[1L * NBDH]; xa1[1] = xpbA[1L * NBDH + 16];
  xa2[0] = xpbA[2L * NBDH]; xa2[1] = xpbA[2L * NBDH + 16];
  xa3[0] = xpbA[3L * NBDH]; xa3[1] = xpbA[3L * NBDH + 16];
  xb0[0] = xpbB[0];         xb0[1] = xpbB[16];
  xb1[0] = xpbB[1L * NBDH]; xb1[1] = xpbB[1L * NBDH + 16];
  xb2[0] = xpbB[2L * NBDH]; xb2[1] = xpbB[2L * NBDH + 16];
  xb3[0] = xpbB[3L * NBDH]; xb3[1] = xpbB[3L * NBDH + 16];

#define M16 __builtin_amdgcn_mfma_f32_16x16x32_bf16
#define RNN_STEP2(T, CUR, XVA, XVB, PF)                                       \
  {                                                                           \
    const short8* apA = (const short8*)(rdpA + (CUR) * 256);                  \
    const short8* apB = (const short8*)(rdpB + (CUR) * 256);                  \
    short8 A0 = apA[0],  A1 = apA[4],  A2 = apA[8],  A3 = apA[12];            \
    short8 A4 = apA[16], A5 = apA[20], A6 = apA[24], A7 = apA[28];            \
    short8 B0 = apB[0],  B1 = apB[4],  B2 = apB[8],  B3 = apB[12];            \
    short8 B4 = apB[16], B5 = apB[20], B6 = apB[24], B7 = apB[28];            \
    f32x4 pa0 = {XVA[0], 0.f, 0.f, 0.f}, pa1 = {XVA[1], 0.f, 0.f, 0.f};       \
    f32x4 pa2 = {0.f, 0.f, 0.f, 0.f},    pa3 = {0.f, 0.f, 0.f, 0.f};          \
    f32x4 pb0 = {XVB[0], 0.f, 0.f, 0.f}, pb1 = {XVB[1], 0.f, 0.f, 0.f};       \
    f32x4 pb2 = {0.f, 0.f, 0.f, 0.f},    pb3 = {0.f, 0.f, 0.f, 0.f};          \
    if (PF) {                                                                 \
      const float* qA = xpbA + (long)((T) + 4) * NBDH;                        \
      const float* qB = xpbB + (long)((T) + 4) * NBDH;                        \
      XVA[0] = qA[0]; XVA[1] = qA[16];                                        \
      XVB[0] = qB[0]; XVB[1] = qB[16];                                        \
    }                                                                         \
    pa0 = M16(A0, bf0[0], pa0, 0, 0, 0); pb0 = M16(B0, bf0[0], pb0, 0, 0, 0); \
    pa1 = M16(A0, bf1[0], pa1, 0, 0, 0); pb1 = M16(B0, bf1[0], pb1, 0, 0, 0); \
    pa2 = M16(A4, bf0[4], pa2, 0, 0, 0); pb2 = M16(B4, bf0[4], pb2, 0, 0, 0); \
    pa3 = M16(A4, bf1[4], pa3, 0, 0, 0); pb3 = M16(B4, bf1[4], pb3, 0, 0, 0); \
    pa0 = M16(A1, bf0[1], pa0, 0, 0, 0); pb0 = M16(B1, bf0[1], pb0, 0, 0, 0); \
    pa1 = M16(A1, bf1[1], pa1, 0, 0, 0); pb1 = M16(B1, bf1[1], pb1, 0, 0, 0); \
    pa2 = M16(A5, bf0[5], pa2, 0, 0, 0); pb2 = M16(B5, bf0[5], pb2, 0, 0, 0); \
    pa3 = M16(A5, bf1[5], pa3, 0, 0, 0); pb3 = M16(B5, bf1[5], pb3, 0, 0, 0); \
    pa0 = M16(A2, bf0[2], pa0, 0, 0, 0); pb0 = M16(B2, bf0[2], pb0, 0, 0, 0); \
    pa1 = M16(A2, bf1[2], pa1, 0, 0, 0); pb1 = M16(B2, bf1[2], pb1, 0, 0, 0); \
    pa2 = M16(A6, bf0[6], pa2, 0, 0, 0); pb2 = M16(B6, bf0[6], pb2, 0, 0, 0); \
    pa3 = M16(A6, bf1[6], pa3, 0, 0, 0); pb3 = M16(B6, bf1[6], pb3, 0, 0, 0); \
    pa0 = M16(A3, bf0[3], pa0, 0, 0, 0); pb0 = M16(B3, bf0[3], pb0, 0, 0, 0); \
    pa1 = M16(A3, bf1[3], pa1, 0, 0, 0); pb1 = M16(B3, bf1[3], pb1, 0, 0, 0); \
    pa2 = M16(A7, bf0[7], pa2, 0, 0, 0); pb2 = M16(B7, bf0[7], pb2, 0, 0, 0); \
    pa3 = M16(A7, bf1[7], pa3, 0, 0, 0); pb3 = M16(B7, bf1[7], pb3, 0, 0, 0); \
    float ta0 = fast_tanh(pa0[0] + pa2[0]);                                   \
    float ta1 = fast_tanh(pa1[0] + pa3[0]);                                   \
    float tb0 = fast_tanh(pb0[0] + pb2[0]);                                   \
    float tb1 = fast_tanh(pb1[0] + pb3[0]);                                   \
    if (l < 16) {                                                             \
      unsigned short ua0 = f2bf(ta0), ua1 = f2bf(ta1);                        \
      unsigned short ub0 = f2bf(tb0), ub1 = f2bf(tb1);                        \
      hA[0][(CUR) ^ 1][w * 32 + l]      = ua0;                                \
      hA[0][(CUR) ^ 1][w * 32 + 16 + l] = ua1;                                \
      hA[1][(CUR) ^ 1][w * 32 + l]      = ub0;                                \
      hA[1][(CUR) ^ 1][w * 32 + 16 + l] = ub1;                                \
      unsigned short* hrA = hsbA + (long)(T) * NBDH;                          \
      unsigned short* hrB = hsbB + (long)(T) * NBDH;                          \
      hrA[0] = ua0; hrA[16] = ua1;                                            \
      hrB[0] = ub0; hrB[16] = ub1;                                            \
    }                                                                         \
    asm volatile("s_waitcnt lgkmcnt(0)" ::: "memory");  /* LDS drain only */  \
    __builtin_amdgcn_s_barrier();                                             \
    __builtin_amdgcn_sched_barrier(0);                                        \
  }

#pragma unroll 1
  for (int t = 0; t < TSTEPS - 4; t += 4) {
    RNN_STEP2(t, 0, xa0, xb0, true);
    RNN_STEP2(t + 1, 1, xa1, xb1, true);
    RNN_STEP2(t + 2, 0, xa2, xb2, true);
    RNN_STEP2(t + 3, 1, xa3, xb3, true);
  }
  RNN_STEP2(TSTEPS - 4, 0, xa0, xb0, false);
  RNN_STEP2(TSTEPS - 3, 1, xa1, xb1, false);
  RNN_STEP2(TSTEPS - 2, 0, xa2, xb2, false);
  RNN_STEP2(TSTEPS - 1, 1, xa3, xb3, false);
#undef RNN_STEP2
#undef M16
}

// ---- kernel 4: h_last = f32(hs[T-1])
__global__ void hlast_k(const unsigned short* __restrict__ hs, float* __restrict__ hlast) {
  int i = blockIdx.x * 1024 + threadIdx.x;          // 16 blocks x 1024 = 16384
  unsigned u = (unsigned)hs[(long)(TSTEPS - 1) * NBDH + i] << 16;
  union { unsigned u; float f; } v; v.u = u;
  hlast[i] = v.f;
}

extern "C" void kernel_launch(void* const* d_in, const int* in_sizes, int n_in,
                              void* d_out, int out_size, void* d_ws, size_t ws_size,
                              hipStream_t stream) {
  const float* x    = (const float*)d_in[0];
  const float* h0   = (const float*)d_in[1];
  const float* Win  = (const float*)d_in[2];
  const float* Whid = (const float*)d_in[3];
  const float* Wout = (const float*)d_in[4];
  float* ys    = (float*)d_out;
  float* hlast = ys + (long)TSTEPS * NB * 256;

  // d_ws layout: [bf16 W_in | bf16 W_hid | bf16 W_out | f32 xp (128MB) | bf16 hs (64MB)]
  unsigned short* wbf     = (unsigned short*)d_ws;
  unsigned short* wbf_in  = wbf;
  unsigned short* wbf_hid = wbf + 65536;
  unsigned short* wbf_out = wbf + 131072;
  float* xproj = (float*)((char*)d_ws + 393216);
  unsigned short* hsbuf =
      (unsigned short*)((char*)d_ws + 393216 + (size_t)TSTEPS * NB * 256 * 4);

  cvt_w<<<dim3(768), dim3(256), 0, stream>>>(Win, Whid, Wout, wbf);
  gemm_nt<false><<<dim3(1024), dim3(256), 0, stream>>>((const void*)x, wbf_in, xproj);
  rnn_scan<<<dim3(32), dim3(512), 0, stream>>>(xproj, wbf_hid, h0, hsbuf);
  gemm_nt<true><<<dim3(1024), dim3(256), 0, stream>>>((const void*)hsbuf, wbf_out, ys);
  hlast_k<<<dim3(16), dim3(1024), 0, stream>>>(hsbuf, hlast);
}